// Round 13
// baseline (295.366 us; speedup 1.0000x reference)
//
#include <hip/hip_runtime.h>
#include <stdint.h>

typedef __bf16 bf16;
typedef __bf16 bf16x8 __attribute__((ext_vector_type(8)));  // 16B
typedef __bf16 bf16x4 __attribute__((ext_vector_type(4)));  // 8B
typedef float  f32x4  __attribute__((ext_vector_type(4)));

#define MFMA_BF16(a, b, c) __builtin_amdgcn_mfma_f32_16x16x32_bf16((a), (b), (c), 0, 0, 0)

static constexpr int BATCH = 2;
static constexpr int SEQ   = 2048;
static constexpr int DIM   = 1024;
static constexpr int HDIM  = 64;
static constexpr int MROWS = BATCH * SEQ;   // 4096

typedef const __attribute__((address_space(1))) void* gvp;
typedef __attribute__((address_space(3))) void* svp;
__device__ __forceinline__ void glds16(const bf16* g, bf16* l) {
    __builtin_amdgcn_global_load_lds((gvp)(const void*)g, (svp)(void*)l, 16, 0, 0);
}

// scan leading nscan u16 of buffer as bf16; any exponent>=0x89 (|x|>=1024 /
// inf / nan) -> fp32 data misread as bf16 (P~0.46 per elem; deterministic
// across blocks since all scan identical bytes). True bf16 here has |x|<6.
__device__ __forceinline__ int scan_f32(const void* p, int nscan, int t) {
    const unsigned short* s = (const unsigned short*)p;
    int local = 0;
    for (int j = t; j < nscan; j += 256)
        local |= (((s[j] >> 7) & 0xFF) >= 0x89) ? 1 : 0;
    return local;
}

__device__ __forceinline__ bf16x8 cvt8(const float4 a, const float4 b) {
    bf16x8 r = {(bf16)a.x, (bf16)a.y, (bf16)a.z, (bf16)a.w,
                (bf16)b.x, (bf16)b.y, (bf16)b.z, (bf16)b.w};
    return r;
}

// ---------------------------------------------------------------------------
// Convert pass (R7 structure): dtype-adaptive fp32|bf16 -> bf16 workspace
// copies. 2052 blocks, 16 KB/block in 4 rounds.
// ---------------------------------------------------------------------------
__global__ __launch_bounds__(256) void convert_kernel(
    const void* __restrict__ q,  const void* __restrict__ k,  const void* __restrict__ v,
    const void* __restrict__ wq, const void* __restrict__ wk, const void* __restrict__ wv,
    const void* __restrict__ wo,
    const void* __restrict__ b_q, const void* __restrict__ b_k,
    const void* __restrict__ b_v, const void* __restrict__ b_o,
    bf16* __restrict__ qd,  bf16* __restrict__ kd,  bf16* __restrict__ vd,
    bf16* __restrict__ wqd, bf16* __restrict__ wkd, bf16* __restrict__ wvd,
    bf16* __restrict__ wod,
    bf16* __restrict__ bqd, bf16* __restrict__ bkd,
    bf16* __restrict__ bvd, bf16* __restrict__ bod,
    int* __restrict__ flagsOut)
{
    const int bid = blockIdx.x;
    int id, chunk;
    if (bid < 1536)      { id = bid >> 9;                chunk = bid & 511; }
    else if (bid < 2048) { id = 3 + ((bid - 1536) >> 7); chunk = (bid - 1536) & 127; }
    else                 { id = 7 + (bid - 2048);        chunk = 0; }

    const void* src; bf16* dst; int nelem, nscan;
    switch (id) {
        case 0:  src = q;   dst = qd;  nelem = 1 << 22; nscan = 4096; break;
        case 1:  src = k;   dst = kd;  nelem = 1 << 22; nscan = 4096; break;
        case 2:  src = v;   dst = vd;  nelem = 1 << 22; nscan = 4096; break;
        case 3:  src = wq;  dst = wqd; nelem = 1 << 20; nscan = 4096; break;
        case 4:  src = wk;  dst = wkd; nelem = 1 << 20; nscan = 4096; break;
        case 5:  src = wv;  dst = wvd; nelem = 1 << 20; nscan = 4096; break;
        case 6:  src = wo;  dst = wod; nelem = 1 << 20; nscan = 4096; break;
        case 7:  src = b_q; dst = bqd; nelem = 1024;    nscan = 1024; break;
        case 8:  src = b_k; dst = bkd; nelem = 1024;    nscan = 1024; break;
        case 9:  src = b_v; dst = bvd; nelem = 1024;    nscan = 1024; break;
        default: src = b_o; dst = bod; nelem = 1024;    nscan = 1024; break;
    }

    __shared__ int sbad;
    const int t = threadIdx.x;
    if (t == 0) sbad = 0;
    __syncthreads();
    int loc = scan_f32(src, nscan, t);
    if (loc) atomicOr(&sbad, 1);
    __syncthreads();
    const bool f32 = sbad != 0;

    if (id == 0 && chunk == 0 && t == 0) flagsOut[0] = f32 ? 1 : 0;

    if (id < 7) {
        const int base0 = chunk * 8192 + t * 8;
        if (f32) {
            const float* s = (const float*)src;
#pragma unroll
            for (int r = 0; r < 4; ++r) {
                const int base = base0 + r * 2048;
                const float4 a  = *(const float4*)(s + base);
                const float4 b2 = *(const float4*)(s + base + 4);
                *(bf16x8*)(dst + base) = cvt8(a, b2);
            }
        } else {
            const bf16* s = (const bf16*)src;
#pragma unroll
            for (int r = 0; r < 4; ++r) {
                const int base = base0 + r * 2048;
                *(bf16x8*)(dst + base) = *(const bf16x8*)(s + base);
            }
        }
    } else {
        const int base = t * 8;
        if (base < nelem) {
            if (f32) {
                const float* s = (const float*)src + base;
                const float4 a  = *(const float4*)s;
                const float4 b2 = *(const float4*)(s + 4);
                *(bf16x8*)(dst + base) = cvt8(a, b2);
            } else {
                *(bf16x8*)(dst + base) = *(const bf16x8*)((const bf16*)src + base);
            }
        }
    }
}

// ---------------------------------------------------------------------------
// QKV GEMM, all-bf16 (m97 structure) + XCD swizzle + setprio (R11).
// ---------------------------------------------------------------------------
__global__ __launch_bounds__(256, 3) void gemm_qkv_kernel(
    const bf16* __restrict__ A0, const bf16* __restrict__ W0,
    const bf16* __restrict__ b0, bf16* __restrict__ C0,
    const bf16* __restrict__ A1, const bf16* __restrict__ W1,
    const bf16* __restrict__ b1, bf16* __restrict__ C1,
    const bf16* __restrict__ A2, const bf16* __restrict__ W2,
    const bf16* __restrict__ b2, bf16* __restrict__ Vtg)
{
    const int z = blockIdx.z;
    const bf16* A  = (z == 0) ? A0 : (z == 1) ? A1 : A2;
    const bf16* W  = (z == 0) ? W0 : (z == 1) ? W1 : W2;
    const bf16* bi = (z == 0) ? b0 : (z == 1) ? b1 : b2;

    __shared__ bf16 As[128 * 32];
    __shared__ bf16 Bs[128 * 32];

    const int t = threadIdx.x;
    const int fid = blockIdx.y * gridDim.x + blockIdx.x;   // 0..255
    const int swz = (fid & 7) * 32 + (fid >> 3);           // XCD-contiguous
    const int n0 = (swz & 7) * 128;
    const int m0 = (swz >> 3) * 128;
    const int w    = t >> 6;
    const int lane = t & 63;
    const int ln   = t & 15;
    const int quad = (t >> 4) & 3;
    const int wm   = (w & 1) * 64;
    const int wn   = (w >> 1) * 64;

    const int srow = w * 32 + (lane >> 2);
    const int scol = (lane & 3) * 8;
    const bf16* gA = A + (size_t)(m0 + srow) * DIM + scol;
    const bf16* gW = W + (size_t)(n0 + srow) * DIM + scol;
    bf16* lA = &As[w * 32 * 32];
    bf16* lW = &Bs[w * 32 * 32];

    f32x4 acc[4][4];
#pragma unroll
    for (int i = 0; i < 4; ++i)
#pragma unroll
        for (int j = 0; j < 4; ++j) acc[i][j] = (f32x4){0.f, 0.f, 0.f, 0.f};

    for (int k0 = 0; k0 < DIM; k0 += 32) {
        __syncthreads();
        glds16(gA + k0,            lA);
        glds16(gA + 16 * DIM + k0, lA + 16 * 32);
        glds16(gW + k0,            lW);
        glds16(gW + 16 * DIM + k0, lW + 16 * 32);
        __syncthreads();

        bf16x8 af[4], bfr[4];
#pragma unroll
        for (int mt = 0; mt < 4; ++mt)
            af[mt] = *(const bf16x8*)&As[(wm + mt * 16 + ln) * 32 + quad * 8];
#pragma unroll
        for (int nt = 0; nt < 4; ++nt)
            bfr[nt] = *(const bf16x8*)&Bs[(wn + nt * 16 + ln) * 32 + quad * 8];
        __builtin_amdgcn_s_setprio(1);
#pragma unroll
        for (int mt = 0; mt < 4; ++mt)
#pragma unroll
            for (int nt = 0; nt < 4; ++nt)
                acc[mt][nt] = MFMA_BF16(af[mt], bfr[nt], acc[mt][nt]);
        __builtin_amdgcn_s_setprio(0);
    }

    if (z == 2) {
        // V epilogue: store transposed per head -> Vt_g[((b*16+h)*64+e)*SEQ + s]
#pragma unroll
        for (int nt = 0; nt < 4; ++nt) {
            const int col = n0 + wn + nt * 16 + ln;       // d
            const int h2 = col >> 6, e = col & 63;
            const float bv = (float)bi[col];
#pragma unroll
            for (int mt = 0; mt < 4; ++mt) {
                const int row = m0 + wm + mt * 16 + quad * 4;
                const int bb = row >> 11, s = row & 2047;
                bf16x4 o = {(bf16)(acc[mt][nt][0] + bv), (bf16)(acc[mt][nt][1] + bv),
                            (bf16)(acc[mt][nt][2] + bv), (bf16)(acc[mt][nt][3] + bv)};
                *(bf16x4*)&Vtg[((size_t)((bb * 16 + h2) * 64 + e)) * SEQ + s] = o;
            }
        }
    } else {
        bf16* C = (z == 0) ? C0 : C1;
#pragma unroll
        for (int nt = 0; nt < 4; ++nt) {
            const int col = n0 + wn + nt * 16 + ln;
            const float bv = (float)bi[col];
#pragma unroll
            for (int mt = 0; mt < 4; ++mt)
#pragma unroll
                for (int r = 0; r < 4; ++r) {
                    const int row = m0 + wm + mt * 16 + quad * 4 + r;
                    C[(size_t)row * DIM + col] = (bf16)(acc[mt][nt][r] + bv);
                }
        }
    }
}

// ---------------------------------------------------------------------------
// Output GEMM (R7 structure) + XCD swizzle + setprio (R11).
// ---------------------------------------------------------------------------
__global__ __launch_bounds__(256, 4) void gemm_out_kernel(
    const bf16* __restrict__ A, const bf16* __restrict__ W,
    const bf16* __restrict__ bi, void* __restrict__ C,
    const int* __restrict__ flags)
{
    __shared__ bf16 As[64 * 32];
    __shared__ bf16 Bs[128 * 32];

    const int t = threadIdx.x;
    const bool of32 = flags[0] != 0;

    const int fid = blockIdx.y * gridDim.x + blockIdx.x;   // 0..511
    const int swz = (fid & 7) * 64 + (fid >> 3);           // XCD-contiguous
    const int n0 = (swz & 7) * 128;
    const int m0 = (swz >> 3) * 64;
    const int w    = t >> 6;
    const int lane = t & 63;
    const int ln   = t & 15;
    const int quad = (t >> 4) & 3;
    const int wm   = (w & 1) * 32;
    const int wn   = (w >> 1) * 64;

    const int arow = w * 16 + (lane >> 2);
    const int wrow = w * 32 + (lane >> 2);
    const int scol = (lane & 3) * 8;
    const bf16* gA = A + (size_t)(m0 + arow) * DIM + scol;
    const bf16* gW = W + (size_t)(n0 + wrow) * DIM + scol;
    bf16* lA = &As[(w * 16) * 32];
    bf16* lW = &Bs[(w * 32) * 32];

    f32x4 acc[2][4];
#pragma unroll
    for (int i = 0; i < 2; ++i)
#pragma unroll
        for (int j = 0; j < 4; ++j) acc[i][j] = (f32x4){0.f, 0.f, 0.f, 0.f};

    for (int k0 = 0; k0 < DIM; k0 += 32) {
        __syncthreads();
        glds16(gA + k0,            lA);
        glds16(gW + k0,            lW);
        glds16(gW + 16 * DIM + k0, lW + 16 * 32);
        __syncthreads();

        bf16x8 af[2], bfr[4];
#pragma unroll
        for (int mt = 0; mt < 2; ++mt)
            af[mt] = *(const bf16x8*)&As[(wm + mt * 16 + ln) * 32 + quad * 8];
#pragma unroll
        for (int nt = 0; nt < 4; ++nt)
            bfr[nt] = *(const bf16x8*)&Bs[(wn + nt * 16 + ln) * 32 + quad * 8];
        __builtin_amdgcn_s_setprio(1);
#pragma unroll
        for (int mt = 0; mt < 2; ++mt)
#pragma unroll
            for (int nt = 0; nt < 4; ++nt)
                acc[mt][nt] = MFMA_BF16(af[mt], bfr[nt], acc[mt][nt]);
        __builtin_amdgcn_s_setprio(0);
    }

#pragma unroll
    for (int nt = 0; nt < 4; ++nt) {
        const int col = n0 + wn + nt * 16 + ln;
        const float bv = (float)bi[col];
#pragma unroll
        for (int mt = 0; mt < 2; ++mt)
#pragma unroll
            for (int r = 0; r < 4; ++r) {
                const int row = m0 + wm + mt * 16 + quad * 4 + r;
                if (of32) ((float*)C)[(size_t)row * DIM + col] = acc[mt][nt][r] + bv;
                else      ((bf16*)C)[(size_t)row * DIM + col] = (bf16)(acc[mt][nt][r] + bv);
            }
    }
}

// ===========================================================================
// ATTENTION common compute macro-free body pieces are duplicated between the
// two variants below (fallback = R11 dbuf full-range; splitk = single-buffer
// half-range with f32 partial outputs).
// ===========================================================================

// ---------------------------------------------------------------------------
// Fallback attention (R11 verbatim): dbuf + counted vmcnt + XCD swizzle +
// setprio + defer-max. 512 blocks, LDS 80 KB, 82.4 us measured.
// ---------------------------------------------------------------------------
__global__ __launch_bounds__(256, 2) void attn_kernel(
    const bf16* __restrict__ Q, const bf16* __restrict__ K,
    const bf16* __restrict__ Vtg, bf16* __restrict__ O)
{
    const int fid = blockIdx.y * gridDim.x + blockIdx.x;   // 0..511
    const int swz = (fid & 7) * 64 + (fid >> 3);           // XCD-contiguous
    const int qt = swz & 15;
    const int bh = swz >> 4;
    const int b  = bh >> 4;
    const int h  = bh & 15;

    __shared__ bf16 Ks[2][128 * 64];
    __shared__ bf16 Vt[2][64 * 128];
    __shared__ bf16 Ps[4 * 16 * 128];

    const int t    = threadIdx.x;
    const int w    = t >> 6;
    const int lane = t & 63;
    const int ln   = lane & 15;
    const int quad = lane >> 4;

    const int q0 = qt * 128;

    const float sc = 0.125f * 1.44269504089f;
    bf16x8 qf[2][2];
#pragma unroll
    for (int g = 0; g < 2; ++g) {
        const bf16* qrow = Q + (size_t)(b * SEQ + q0 + w * 32 + g * 16 + ln) * DIM + h * HDIM;
        qf[g][0] = *(const bf16x8*)(qrow + quad * 8);
        qf[g][1] = *(const bf16x8*)(qrow + 32 + quad * 8);
#pragma unroll
        for (int i = 0; i < 8; ++i) {
            qf[g][0][i] = (bf16)((float)qf[g][0][i] * sc);
            qf[g][1][i] = (bf16)((float)qf[g][1][i] * sc);
        }
    }

    f32x4 o_acc[2][4];
#pragma unroll
    for (int g = 0; g < 2; ++g)
#pragma unroll
        for (int c = 0; c < 4; ++c) o_acc[g][c] = (f32x4){0.f, 0.f, 0.f, 0.f};
    float m_s[2] = {-1e30f, -1e30f};
    float l_s[2] = {0.f, 0.f};

    const int kr_off = lane >> 3;
    const int k_lc   = (lane & 7) ^ kr_off;
    const int ve_off = lane >> 4;
    const int v_pc   = lane & 15;
    const size_t vrowbase = (size_t)((b * 16 + h) * 64);

    const int psbase = (w * 16 + ln) * 128;
    const int pmask  = (ln & 15) << 1;

#define STAGE_KV(BUF, KB)                                                     \
    {                                                                         \
        _Pragma("unroll")                                                     \
        for (int i = 0; i < 4; ++i) {                                         \
            const int r = w * 32 + i * 8 + kr_off;                            \
            glds16(K + (size_t)(b * SEQ + (KB) + r) * DIM + h * HDIM + k_lc * 8, \
                   &Ks[BUF][(w * 32 + i * 8) * 64]);                          \
        }                                                                     \
        _Pragma("unroll")                                                     \
        for (int i = 0; i < 4; ++i) {                                         \
            const int e2 = w * 16 + i * 4 + ve_off;                           \
            const int lc = v_pc ^ (i * 4 + ve_off);                           \
            glds16(Vtg + (vrowbase + e2) * SEQ + (KB) + lc * 8,               \
                   &Vt[BUF][(w * 16 + i * 4) * 128]);                         \
        }                                                                     \
    }

    STAGE_KV(0, 0);

    for (int it = 0; it < SEQ / 128; ++it) {
        const int cur = it & 1;
        if (it < SEQ / 128 - 1) {
            STAGE_KV(cur ^ 1, (it + 1) * 128);
            __asm__ volatile("s_waitcnt vmcnt(8)" ::: "memory");
        } else {
            __asm__ volatile("s_waitcnt vmcnt(0)" ::: "memory");
        }
        __builtin_amdgcn_sched_barrier(0);
        __builtin_amdgcn_s_barrier();
        __builtin_amdgcn_sched_barrier(0);

        f32x4 sa0[8], sa1[8];
        __builtin_amdgcn_s_setprio(1);
#pragma unroll
        for (int nt = 0; nt < 8; ++nt) {
            const int rr = (nt * 16 + ln) * 64;
            const bf16x8 kf0 = *(const bf16x8*)&Ks[cur][rr + ((quad ^ (ln & 7)) << 3)];
            const bf16x8 kf1 = *(const bf16x8*)&Ks[cur][rr + (((quad + 4) ^ (ln & 7)) << 3)];
            f32x4 z0 = (f32x4){0.f, 0.f, 0.f, 0.f};
            z0 = MFMA_BF16(kf0, qf[0][0], z0);
            z0 = MFMA_BF16(kf1, qf[0][1], z0);
            sa0[nt] = z0;
            f32x4 z1 = (f32x4){0.f, 0.f, 0.f, 0.f};
            z1 = MFMA_BF16(kf0, qf[1][0], z1);
            z1 = MFMA_BF16(kf1, qf[1][1], z1);
            sa1[nt] = z1;
        }
        __builtin_amdgcn_s_setprio(0);

#pragma unroll
        for (int g = 0; g < 2; ++g) {
            f32x4* sa = g ? sa1 : sa0;
            float m8[8];
#pragma unroll
            for (int nt = 0; nt < 8; ++nt)
                m8[nt] = fmaxf(fmaxf(sa[nt][0], sa[nt][1]), fmaxf(sa[nt][2], sa[nt][3]));
            float mx = fmaxf(fmaxf(fmaxf(m8[0], m8[1]), fmaxf(m8[2], m8[3])),
                             fmaxf(fmaxf(m8[4], m8[5]), fmaxf(m8[6], m8[7])));
            mx = fmaxf(mx, __shfl_xor(mx, 16));
            mx = fmaxf(mx, __shfl_xor(mx, 32));
            if (!__all(mx <= m_s[g])) {
                const float mn = fmaxf(m_s[g], mx);
                const float al = exp2f(m_s[g] - mn);
                m_s[g] = mn;
                l_s[g] *= al;
#pragma unroll
                for (int r = 0; r < 4; ++r) {
                    const float alr = __shfl(al, quad * 4 + r);
#pragma unroll
                    for (int c = 0; c < 4; ++c) o_acc[g][c][r] *= alr;
                }
            }
            const float mn = m_s[g];
            float r8[8];
#pragma unroll
            for (int nt = 0; nt < 8; ++nt) {
                float p0 = exp2f(sa[nt][0] - mn);
                float p1 = exp2f(sa[nt][1] - mn);
                float p2 = exp2f(sa[nt][2] - mn);
                float p3 = exp2f(sa[nt][3] - mn);
                sa[nt][0] = p0; sa[nt][1] = p1; sa[nt][2] = p2; sa[nt][3] = p3;
                r8[nt] = (p0 + p1) + (p2 + p3);
            }
            float rs = ((r8[0] + r8[1]) + (r8[2] + r8[3])) +
                       ((r8[4] + r8[5]) + (r8[6] + r8[7]));
            rs += __shfl_xor(rs, 16);
            rs += __shfl_xor(rs, 32);
            l_s[g] += rs;
        }

#pragma unroll
        for (int nt = 0; nt < 8; ++nt) {
            bf16x4 pk = {(bf16)sa0[nt][0], (bf16)sa0[nt][1],
                         (bf16)sa0[nt][2], (bf16)sa0[nt][3]};
            *(bf16x4*)&Ps[psbase + (((nt * 4 + quad) ^ pmask) << 2)] = pk;
        }
        __asm__ volatile("s_waitcnt lgkmcnt(0)" ::: "memory");
        bf16x8 pf0[4];
#pragma unroll
        for (int kc = 0; kc < 4; ++kc)
            pf0[kc] = *(const bf16x8*)&Ps[psbase + (((kc * 8 + quad * 2) ^ pmask) << 2)];
        __asm__ volatile("s_waitcnt lgkmcnt(0)" ::: "memory");
#pragma unroll
        for (int nt = 0; nt < 8; ++nt) {
            bf16x4 pk = {(bf16)sa1[nt][0], (bf16)sa1[nt][1],
                         (bf16)sa1[nt][2], (bf16)sa1[nt][3]};
            *(bf16x4*)&Ps[psbase + (((nt * 4 + quad) ^ pmask) << 2)] = pk;
        }
        bf16x8 vf[4][4];
#pragma unroll
        for (int kc = 0; kc < 4; ++kc)
#pragma unroll
            for (int c = 0; c < 4; ++c) {
                const int e = c * 16 + ln;
                const int pc = (kc * 4 + quad) ^ ln;
                vf[kc][c] = *(const bf16x8*)&Vt[cur][e * 128 + pc * 8];
            }
        __asm__ volatile("s_waitcnt lgkmcnt(0)" ::: "memory");

        __builtin_amdgcn_s_setprio(1);
#pragma unroll
        for (int kc = 0; kc < 4; ++kc)
#pragma unroll
            for (int c = 0; c < 4; ++c)
                o_acc[0][c] = MFMA_BF16(pf0[kc], vf[kc][c], o_acc[0][c]);
        __builtin_amdgcn_s_setprio(0);
        bf16x8 pf1[4];
#pragma unroll
        for (int kc = 0; kc < 4; ++kc)
            pf1[kc] = *(const bf16x8*)&Ps[psbase + (((kc * 8 + quad * 2) ^ pmask) << 2)];
        __asm__ volatile("s_waitcnt lgkmcnt(0)" ::: "memory");
        __builtin_amdgcn_s_setprio(1);
#pragma unroll
        for (int kc = 0; kc < 4; ++kc)
#pragma unroll
            for (int c = 0; c < 4; ++c)
                o_acc[1][c] = MFMA_BF16(pf1[kc], vf[kc][c], o_acc[1][c]);
        __builtin_amdgcn_s_setprio(0);

        __builtin_amdgcn_sched_barrier(0);
        __builtin_amdgcn_s_barrier();
    }
#undef STAGE_KV

#pragma unroll
    for (int g = 0; g < 2; ++g) {
        const float linv = 1.0f / l_s[g];
#pragma unroll
        for (int r = 0; r < 4; ++r) {
            const float lr = __shfl(linv, quad * 4 + r);
            const size_t rowoff =
                (size_t)(b * SEQ + q0 + w * 32 + g * 16 + quad * 4 + r) * DIM + h * HDIM;
#pragma unroll
            for (int c = 0; c < 4; ++c)
                O[rowoff + c * 16 + ln] = (bf16)(o_acc[g][c][r] * lr);
        }
    }
}

// ---------------------------------------------------------------------------
// Split-K attention: z in {0,1} halves of the k-range (8 tiles each).
// Single-buffered K/V (staging is L2-hit post-swizzle; dbuf insurance not
// needed) + HALF-size per-wave Ps (R3's proven 16q x 64k, 8B-slot XOR,
// two PV half-passes per group) -> LDS = 16+16+8 = 40 KB -> 4 blocks/CU,
// tail-free with 1024 blocks. NO launch hint (R8/R9: hints force spill).
// Outputs UN-normalized f32 partials + per-row m,l for the combine kernel.
// ---------------------------------------------------------------------------
__global__ __launch_bounds__(256) void attn_splitk_kernel(
    const bf16* __restrict__ Q, const bf16* __restrict__ K,
    const bf16* __restrict__ Vtg,
    float* __restrict__ Op, float* __restrict__ Mp, float* __restrict__ Lp)
{
    const int z   = blockIdx.z;                            // k-half
    const int fid = blockIdx.y * gridDim.x + blockIdx.x;   // 0..511
    const int swz = (fid & 7) * 64 + (fid >> 3);           // XCD-contiguous
    const int qt = swz & 15;
    const int bh = swz >> 4;
    const int b  = bh >> 4;
    const int h  = bh & 15;
    const int pidx = bh * 16 + qt;                         // 0..511
    const int kb0  = z * (SEQ / 2);

    __shared__ bf16 Ks[128 * 64];     // 16 KB
    __shared__ bf16 Vt[64 * 128];     // 16 KB
    __shared__ bf16 Ps[4 * 16 * 64];  // 8 KB, per-wave 16q x 64k half

    const int t    = threadIdx.x;
    const int w    = t >> 6;
    const int lane = t & 63;
    const int ln   = lane & 15;
    const int quad = lane >> 4;

    const int q0 = qt * 128;

    const float sc = 0.125f * 1.44269504089f;
    bf16x8 qf[2][2];
#pragma unroll
    for (int g = 0; g < 2; ++g) {
        const bf16* qrow = Q + (size_t)(b * SEQ + q0 + w * 32 + g * 16 + ln) * DIM + h * HDIM;
        qf[g][0] = *(const bf16x8*)(qrow + quad * 8);
        qf[g][1] = *(const bf16x8*)(qrow + 32 + quad * 8);
#pragma unroll
        for (int i = 0; i < 8; ++i) {
            qf[g][0][i] = (bf16)((float)qf[g][0][i] * sc);
            qf[g][1][i] = (bf16)((float)qf[g][1][i] * sc);
        }
    }

    f32x4 o_acc[2][4];
#pragma unroll
    for (int g = 0; g < 2; ++g)
#pragma unroll
        for (int c = 0; c < 4; ++c) o_acc[g][c] = (f32x4){0.f, 0.f, 0.f, 0.f};
    float m_s[2] = {-1e30f, -1e30f};
    float l_s[2] = {0.f, 0.f};

    const int kr_off = lane >> 3;
    const int k_lc   = (lane & 7) ^ kr_off;
    const int ve_off = lane >> 4;
    const int v_pc   = lane & 15;
    const size_t vrowbase = (size_t)((b * 16 + h) * 64);

    const int psbase = (w * 16 + ln) * 64;      // half-buffer row, stride 64
    const int pmask  = (ln & 7) << 1;           // 8B-slot XOR (R3, proven)

    for (int it = 0; it < 8; ++it) {
        const int kb = kb0 + it * 128;
        __syncthreads();              // prev-iter Ks/Vt reads complete
#pragma unroll
        for (int i = 0; i < 4; ++i) {
            const int r = w * 32 + i * 8 + kr_off;
            glds16(K + (size_t)(b * SEQ + kb + r) * DIM + h * HDIM + k_lc * 8,
                   &Ks[(w * 32 + i * 8) * 64]);
        }
#pragma unroll
        for (int i = 0; i < 4; ++i) {
            const int e2 = w * 16 + i * 4 + ve_off;
            const int lc = v_pc ^ (i * 4 + ve_off);
            glds16(Vtg + (vrowbase + e2) * SEQ + kb + lc * 8,
                   &Vt[(w * 16 + i * 4) * 128]);
        }
        __syncthreads();              // staged tile visible

        // ---- S^T = K·Q^T for both q-groups
        f32x4 sa0[8], sa1[8];
        __builtin_amdgcn_s_setprio(1);
#pragma unroll
        for (int nt = 0; nt < 8; ++nt) {
            const int rr = (nt * 16 + ln) * 64;
            const bf16x8 kf0 = *(const bf16x8*)&Ks[rr + ((quad ^ (ln & 7)) << 3)];
            const bf16x8 kf1 = *(const bf16x8*)&Ks[rr + (((quad + 4) ^ (ln & 7)) << 3)];
            f32x4 z0 = (f32x4){0.f, 0.f, 0.f, 0.f};
            z0 = MFMA_BF16(kf0, qf[0][0], z0);
            z0 = MFMA_BF16(kf1, qf[0][1], z0);
            sa0[nt] = z0;
            f32x4 z1 = (f32x4){0.f, 0.f, 0.f, 0.f};
            z1 = MFMA_BF16(kf0, qf[1][0], z1);
            z1 = MFMA_BF16(kf1, qf[1][1], z1);
            sa1[nt] = z1;
        }
        __builtin_amdgcn_s_setprio(0);

        // ---- online softmax with defer-max THR=0
#pragma unroll
        for (int g = 0; g < 2; ++g) {
            f32x4* sa = g ? sa1 : sa0;
            float m8[8];
#pragma unroll
            for (int nt = 0; nt < 8; ++nt)
                m8[nt] = fmaxf(fmaxf(sa[nt][0], sa[nt][1]), fmaxf(sa[nt][2], sa[nt][3]));
            float mx = fmaxf(fmaxf(fmaxf(m8[0], m8[1]), fmaxf(m8[2], m8[3])),
                             fmaxf(fmaxf(m8[4], m8[5]), fmaxf(m8[6], m8[7])));
            mx = fmaxf(mx, __shfl_xor(mx, 16));
            mx = fmaxf(mx, __shfl_xor(mx, 32));
            if (!__all(mx <= m_s[g])) {
                const float mn = fmaxf(m_s[g], mx);
                const float al = exp2f(m_s[g] - mn);
                m_s[g] = mn;
                l_s[g] *= al;
#pragma unroll
                for (int r = 0; r < 4; ++r) {
                    const float alr = __shfl(al, quad * 4 + r);
#pragma unroll
                    for (int c = 0; c < 4; ++c) o_acc[g][c][r] *= alr;
                }
            }
            const float mn = m_s[g];
            float r8[8];
#pragma unroll
            for (int nt = 0; nt < 8; ++nt) {
                float p0 = exp2f(sa[nt][0] - mn);
                float p1 = exp2f(sa[nt][1] - mn);
                float p2 = exp2f(sa[nt][2] - mn);
                float p3 = exp2f(sa[nt][3] - mn);
                sa[nt][0] = p0; sa[nt][1] = p1; sa[nt][2] = p2; sa[nt][3] = p3;
                r8[nt] = (p0 + p1) + (p2 + p3);
            }
            float rs = ((r8[0] + r8[1]) + (r8[2] + r8[3])) +
                       ((r8[4] + r8[5]) + (r8[6] + r8[7]));
            rs += __shfl_xor(rs, 16);
            rs += __shfl_xor(rs, 32);
            l_s[g] += rs;
        }

        // ---- PV via half-size Ps, two half-passes per group (R3 structure)
        bf16x8 vf[4][4];   // loaded lazily: vf[0..1] (half A), vf[2..3] (half B)
#pragma unroll
        for (int g = 0; g < 2; ++g) {
            f32x4* sa = g ? sa1 : sa0;
            // half A writes: k 0..63 (nt 0..3)
#pragma unroll
            for (int nt = 0; nt < 4; ++nt) {
                bf16x4 pk = {(bf16)sa[nt][0], (bf16)sa[nt][1],
                             (bf16)sa[nt][2], (bf16)sa[nt][3]};
                *(bf16x4*)&Ps[psbase + (((nt * 4 + quad) ^ pmask) << 2)] = pk;
            }
            __asm__ volatile("s_waitcnt lgkmcnt(0)" ::: "memory");
            bf16x8 pfA[2];
#pragma unroll
            for (int kc = 0; kc < 2; ++kc)
                pfA[kc] = *(const bf16x8*)&Ps[psbase + (((kc * 8 + quad * 2) ^ pmask) << 2)];
            if (g == 0) {
#pragma unroll
                for (int kc = 0; kc < 2; ++kc)
#pragma unroll
                    for (int c = 0; c < 4; ++c) {
                        const int e = c * 16 + ln;
                        const int pc = (kc * 4 + quad) ^ ln;
                        vf[kc][c] = *(const bf16x8*)&Vt[e * 128 + pc * 8];
                    }
            }
            __asm__ volatile("s_waitcnt lgkmcnt(0)" ::: "memory");
            // half B writes overlap half-A MFMAs: k 64..127 (nt 4..7)
#pragma unroll
            for (int nt = 4; nt < 8; ++nt) {
                bf16x4 pk = {(bf16)sa[nt][0], (bf16)sa[nt][1],
                             (bf16)sa[nt][2], (bf16)sa[nt][3]};
                *(bf16x4*)&Ps[psbase + ((((nt - 4) * 4 + quad) ^ pmask) << 2)] = pk;
            }
            __builtin_amdgcn_s_setprio(1);
#pragma unroll
            for (int kc = 0; kc < 2; ++kc)
#pragma unroll
                for (int c = 0; c < 4; ++c)
                    o_acc[g][c] = MFMA_BF16(pfA[kc], vf[kc][c], o_acc[g][c]);
            __builtin_amdgcn_s_setprio(0);
            __asm__ volatile("s_waitcnt lgkmcnt(0)" ::: "memory");
            bf16x8 pfB[2];
#pragma unroll
            for (int kc = 0; kc < 2; ++kc)
                pfB[kc] = *(const bf16x8*)&Ps[psbase + (((kc * 8 + quad * 2) ^ pmask) << 2)];
            if (g == 0) {
#pragma unroll
                for (int kc = 2; kc < 4; ++kc)
#pragma unroll
                    for (int c = 0; c < 4; ++c) {
                        const int e = c * 16 + ln;
                        const int pc = (kc * 4 + quad) ^ ln;
                        vf[kc][c] = *(const bf16x8*)&Vt[e * 128 + pc * 8];
                    }
            }
            __asm__ volatile("s_waitcnt lgkmcnt(0)" ::: "memory");
            __builtin_amdgcn_s_setprio(1);
#pragma unroll
            for (int kc = 0; kc < 2; ++kc)
#pragma unroll
                for (int c = 0; c < 4; ++c)
                    o_acc[g][c] = MFMA_BF16(pfB[kc], vf[kc + 2][c], o_acc[g][c]);
            __builtin_amdgcn_s_setprio(0);
        }
    }

    // ---- epilogue: store UN-normalized f32 partials + m/l per q-row
    const size_t obase = (size_t)(z * 512 + pidx) * 128 * 64;
#pragma unroll
    for (int g = 0; g < 2; ++g) {
#pragma unroll
        for (int r = 0; r < 4; ++r) {
            const int q = w * 32 + g * 16 + quad * 4 + r;
#pragma unroll
            for (int c = 0; c < 4; ++c)
                Op[obase + (size_t)q * 64 + c * 16 + ln] = o_acc[g][c][r];
        }
        if (quad == 0) {
            const int q = w * 32 + g * 16 + ln;
            Mp[(size_t)(z * 512 + pidx) * 128 + q] = m_s[g];
            Lp[(size_t)(z * 512 + pidx) * 128 + q] = l_s[g];
        }
    }
}

// ---------------------------------------------------------------------------
// Combine: O = (O0*2^{m0-m} + O1*2^{m1-m}) / (l0*2^{m0-m} + l1*2^{m1-m}),
// m = max(m0,m1). Memory-bound (~42 MB). Grid (512, 4): block = (pidx,
// 32-row chunk); thread t -> row t>>3, elems (t&7)*8..+7.
// ---------------------------------------------------------------------------
__global__ __launch_bounds__(256) void attn_combine_kernel(
    const float* __restrict__ Op, const float* __restrict__ Mp,
    const float* __restrict__ Lp, bf16* __restrict__ O)
{
    const int pidx = blockIdx.x;
    const int t = threadIdx.x;
    const int ri = blockIdx.y * 32 + (t >> 3);
    const int e0 = (t & 7) * 8;
    const int bh = pidx >> 4, qt = pidx & 15;
    const int b = bh >> 4, h = bh & 15;

    const size_t r0 = (size_t)pidx * 128 + ri;
    const size_t r1 = (size_t)(512 + pidx) * 128 + ri;
    const float m0 = Mp[r0], m1 = Mp[r1];
    const float l0 = Lp[r0], l1 = Lp[r1];
    const float m  = fmaxf(m0, m1);
    const float w0 = exp2f(m0 - m), w1 = exp2f(m1 - m);
    const float inv = 1.0f / (l0 * w0 + l1 * w1);

    const float* p0 = Op + r0 * 64 + e0;
    const float* p1 = Op + r1 * 64 + e0;
    const float4 a0 = *(const float4*)p0;
    const float4 a1 = *(const float4*)(p0 + 4);
    const float4 c0 = *(const float4*)p1;
    const float4 c1 = *(const float4*)(p1 + 4);

    bf16x8 out;
    out[0] = (bf16)((a0.x * w0 + c0.x * w1) * inv);
    out[1] = (bf16)((a0.y * w0 + c0.y * w1) * inv);
    out[2] = (bf16)((a0.z * w0 + c0.z * w1) * inv);
    out[3] = (bf16)((a0.w * w0 + c0.w * w1) * inv);
    out[4] = (bf16)((a1.x * w0 + c1.x * w1) * inv);
    out[5] = (bf16)((a1.y * w0 + c1.y * w1) * inv);
    out[6] = (bf16)((a1.z * w0 + c1.z * w1) * inv);
    out[7] = (bf16)((a1.w * w0 + c1.w * w1) * inv);

    const int s = qt * 128 + ri;
    *(bf16x8*)(O + (size_t)(b * SEQ + s) * DIM + h * HDIM + e0) = out;
}

extern "C" void kernel_launch(void* const* d_in, const int* in_sizes, int n_in,
                              void* d_out, int out_size, void* d_ws, size_t ws_size,
                              hipStream_t stream) {
    // ws layout (bf16 elems): Qb,Kb,Vtg (4.19M each), qc,kc,vc (4.19M each;
    // qc re-used as Ob), Wq..Wo (1.05M each), biases, flags (~59 MB), then an
    // OPTIONAL f32 split-K extension (~34.5 MB) used only if ws_size permits.
    const size_t NM = (size_t)MROWS * DIM;     // 4194304
    const size_t NW = (size_t)DIM * DIM;       // 1048576
    bf16* Qb  = (bf16*)d_ws;
    bf16* Kb  = Qb + NM;
    bf16* Vtg = Kb + NM;
    bf16* qc  = Vtg + NM;
    bf16* kc  = qc + NM;
    bf16* vc  = kc + NM;
    bf16* Wqc = vc + NM;
    bf16* Wkc = Wqc + NW;
    bf16* Wvc = Wkc + NW;
    bf16* Woc = Wvc + NW;
    bf16* bqc = Woc + NW;
    bf16* bkc = bqc + 1024;
    bf16* bvc = bkc + 1024;
    bf16* boc = bvc + 1024;
    int*  flags = (int*)(boc + 1024);
    bf16* Ob  = qc;   // alias: qc dead after gemm_qkv, Ob written by attn

    // split-K extension (f32), 256B-aligned after flags
    uintptr_t ext = ((uintptr_t)(flags + 4) + 255) & ~(uintptr_t)255;
    float* Op = (float*)ext;                       // 2*512*128*64 = 33.55 MB
    float* Mp = Op + (size_t)2 * 512 * 128 * 64;   // 0.5 MB
    float* Lp = Mp + (size_t)2 * 512 * 128;        // 0.5 MB
    const size_t needed = (size_t)((uintptr_t)(Lp + (size_t)2 * 512 * 128)
                                   - (uintptr_t)d_ws);
    const bool use_splitk = (ws_size >= needed);

    convert_kernel<<<dim3(2052), 256, 0, stream>>>(
        d_in[0], d_in[1], d_in[2],
        d_in[3], d_in[5], d_in[7], d_in[9],
        d_in[4], d_in[6], d_in[8], d_in[10],
        qc, kc, vc, Wqc, Wkc, Wvc, Woc, bqc, bkc, bvc, boc, flags);

    gemm_qkv_kernel<<<dim3(DIM / 128, MROWS / 128, 3), 256, 0, stream>>>(
        qc, Wqc, bqc, Qb,
        kc, Wkc, bkc, Kb,
        vc, Wvc, bvc, Vtg);

    if (use_splitk) {
        attn_splitk_kernel<<<dim3(SEQ / 128, BATCH * 16, 2), 256, 0, stream>>>(
            Qb, Kb, Vtg, Op, Mp, Lp);
        attn_combine_kernel<<<dim3(512, 4), 256, 0, stream>>>(Op, Mp, Lp, Ob);
    } else {
        attn_kernel<<<dim3(SEQ / 128, BATCH * 16), 256, 0, stream>>>(Qb, Kb, Vtg, Ob);
    }

    gemm_out_kernel<<<dim3(DIM / 128, MROWS / 64), 256, 0, stream>>>(
        Ob, Woc, boc, d_out, flags);
}

// Round 14
// 244.738 us; speedup vs baseline: 1.2069x; 1.2069x over previous
//
#include <hip/hip_runtime.h>
#include <stdint.h>

typedef __bf16 bf16;
typedef __bf16 bf16x8 __attribute__((ext_vector_type(8)));  // 16B
typedef __bf16 bf16x4 __attribute__((ext_vector_type(4)));  // 8B
typedef float  f32x4  __attribute__((ext_vector_type(4)));

#define MFMA_BF16(a, b, c) __builtin_amdgcn_mfma_f32_16x16x32_bf16((a), (b), (c), 0, 0, 0)

static constexpr int BATCH = 2;
static constexpr int SEQ   = 2048;
static constexpr int DIM   = 1024;
static constexpr int HDIM  = 64;
static constexpr int MROWS = BATCH * SEQ;   // 4096

typedef const __attribute__((address_space(1))) void* gvp;
typedef __attribute__((address_space(3))) void* svp;
__device__ __forceinline__ void glds16(const bf16* g, bf16* l) {
    __builtin_amdgcn_global_load_lds((gvp)(const void*)g, (svp)(void*)l, 16, 0, 0);
}

// scan leading nscan u16 of buffer as bf16; any exponent>=0x89 (|x|>=1024 /
// inf / nan) -> fp32 data misread as bf16 (P~0.46 per elem; deterministic
// across blocks since all scan identical bytes). True bf16 here has |x|<6.
__device__ __forceinline__ int scan_f32(const void* p, int nscan, int t) {
    const unsigned short* s = (const unsigned short*)p;
    int local = 0;
    for (int j = t; j < nscan; j += 256)
        local |= (((s[j] >> 7) & 0xFF) >= 0x89) ? 1 : 0;
    return local;
}

__device__ __forceinline__ bf16x8 cvt8(const float4 a, const float4 b) {
    bf16x8 r = {(bf16)a.x, (bf16)a.y, (bf16)a.z, (bf16)a.w,
                (bf16)b.x, (bf16)b.y, (bf16)b.z, (bf16)b.w};
    return r;
}

// ---------------------------------------------------------------------------
// Convert pass (R7 structure): dtype-adaptive fp32|bf16 -> bf16 workspace
// copies. 2052 blocks, 16 KB/block in 4 rounds.
// ---------------------------------------------------------------------------
__global__ __launch_bounds__(256) void convert_kernel(
    const void* __restrict__ q,  const void* __restrict__ k,  const void* __restrict__ v,
    const void* __restrict__ wq, const void* __restrict__ wk, const void* __restrict__ wv,
    const void* __restrict__ wo,
    const void* __restrict__ b_q, const void* __restrict__ b_k,
    const void* __restrict__ b_v, const void* __restrict__ b_o,
    bf16* __restrict__ qd,  bf16* __restrict__ kd,  bf16* __restrict__ vd,
    bf16* __restrict__ wqd, bf16* __restrict__ wkd, bf16* __restrict__ wvd,
    bf16* __restrict__ wod,
    bf16* __restrict__ bqd, bf16* __restrict__ bkd,
    bf16* __restrict__ bvd, bf16* __restrict__ bod,
    int* __restrict__ flagsOut)
{
    const int bid = blockIdx.x;
    int id, chunk;
    if (bid < 1536)      { id = bid >> 9;                chunk = bid & 511; }
    else if (bid < 2048) { id = 3 + ((bid - 1536) >> 7); chunk = (bid - 1536) & 127; }
    else                 { id = 7 + (bid - 2048);        chunk = 0; }

    const void* src; bf16* dst; int nelem, nscan;
    switch (id) {
        case 0:  src = q;   dst = qd;  nelem = 1 << 22; nscan = 4096; break;
        case 1:  src = k;   dst = kd;  nelem = 1 << 22; nscan = 4096; break;
        case 2:  src = v;   dst = vd;  nelem = 1 << 22; nscan = 4096; break;
        case 3:  src = wq;  dst = wqd; nelem = 1 << 20; nscan = 4096; break;
        case 4:  src = wk;  dst = wkd; nelem = 1 << 20; nscan = 4096; break;
        case 5:  src = wv;  dst = wvd; nelem = 1 << 20; nscan = 4096; break;
        case 6:  src = wo;  dst = wod; nelem = 1 << 20; nscan = 4096; break;
        case 7:  src = b_q; dst = bqd; nelem = 1024;    nscan = 1024; break;
        case 8:  src = b_k; dst = bkd; nelem = 1024;    nscan = 1024; break;
        case 9:  src = b_v; dst = bvd; nelem = 1024;    nscan = 1024; break;
        default: src = b_o; dst = bod; nelem = 1024;    nscan = 1024; break;
    }

    __shared__ int sbad;
    const int t = threadIdx.x;
    if (t == 0) sbad = 0;
    __syncthreads();
    int loc = scan_f32(src, nscan, t);
    if (loc) atomicOr(&sbad, 1);
    __syncthreads();
    const bool f32 = sbad != 0;

    if (id == 0 && chunk == 0 && t == 0) flagsOut[0] = f32 ? 1 : 0;

    if (id < 7) {
        const int base0 = chunk * 8192 + t * 8;
        if (f32) {
            const float* s = (const float*)src;
#pragma unroll
            for (int r = 0; r < 4; ++r) {
                const int base = base0 + r * 2048;
                const float4 a  = *(const float4*)(s + base);
                const float4 b2 = *(const float4*)(s + base + 4);
                *(bf16x8*)(dst + base) = cvt8(a, b2);
            }
        } else {
            const bf16* s = (const bf16*)src;
#pragma unroll
            for (int r = 0; r < 4; ++r) {
                const int base = base0 + r * 2048;
                *(bf16x8*)(dst + base) = *(const bf16x8*)(s + base);
            }
        }
    } else {
        const int base = t * 8;
        if (base < nelem) {
            if (f32) {
                const float* s = (const float*)src + base;
                const float4 a  = *(const float4*)s;
                const float4 b2 = *(const float4*)(s + 4);
                *(bf16x8*)(dst + base) = cvt8(a, b2);
            } else {
                *(bf16x8*)(dst + base) = *(const bf16x8*)((const bf16*)src + base);
            }
        }
    }
}

// ---------------------------------------------------------------------------
// QKV GEMM, all-bf16 (m97 structure) + XCD-aware tile swizzle (T1): per
// z-slice, flat id f -> swz=(f%8)*32+f/8 (bijective, 256%8==0) so each XCD's
// ~32 consecutive blocks share 4 A-panels (1 MB) and all W-tiles (2 MB) in
// its private L2. C = A @ W^T + bias; z==2 stores V transposed per head.
// ---------------------------------------------------------------------------
__global__ __launch_bounds__(256, 3) void gemm_qkv_kernel(
    const bf16* __restrict__ A0, const bf16* __restrict__ W0,
    const bf16* __restrict__ b0, bf16* __restrict__ C0,
    const bf16* __restrict__ A1, const bf16* __restrict__ W1,
    const bf16* __restrict__ b1, bf16* __restrict__ C1,
    const bf16* __restrict__ A2, const bf16* __restrict__ W2,
    const bf16* __restrict__ b2, bf16* __restrict__ Vtg)
{
    const int z = blockIdx.z;
    const bf16* A  = (z == 0) ? A0 : (z == 1) ? A1 : A2;
    const bf16* W  = (z == 0) ? W0 : (z == 1) ? W1 : W2;
    const bf16* bi = (z == 0) ? b0 : (z == 1) ? b1 : b2;

    __shared__ bf16 As[128 * 32];
    __shared__ bf16 Bs[128 * 32];

    const int t = threadIdx.x;
    const int fid = blockIdx.y * gridDim.x + blockIdx.x;   // 0..255
    const int swz = (fid & 7) * 32 + (fid >> 3);           // XCD-contiguous
    const int n0 = (swz & 7) * 128;
    const int m0 = (swz >> 3) * 128;
    const int w    = t >> 6;
    const int lane = t & 63;
    const int ln   = t & 15;
    const int quad = (t >> 4) & 3;
    const int wm   = (w & 1) * 64;
    const int wn   = (w >> 1) * 64;

    const int srow = w * 32 + (lane >> 2);
    const int scol = (lane & 3) * 8;
    const bf16* gA = A + (size_t)(m0 + srow) * DIM + scol;
    const bf16* gW = W + (size_t)(n0 + srow) * DIM + scol;
    bf16* lA = &As[w * 32 * 32];
    bf16* lW = &Bs[w * 32 * 32];

    f32x4 acc[4][4];
#pragma unroll
    for (int i = 0; i < 4; ++i)
#pragma unroll
        for (int j = 0; j < 4; ++j) acc[i][j] = (f32x4){0.f, 0.f, 0.f, 0.f};

    for (int k0 = 0; k0 < DIM; k0 += 32) {
        __syncthreads();
        glds16(gA + k0,            lA);
        glds16(gA + 16 * DIM + k0, lA + 16 * 32);
        glds16(gW + k0,            lW);
        glds16(gW + 16 * DIM + k0, lW + 16 * 32);
        __syncthreads();

        bf16x8 af[4], bfr[4];
#pragma unroll
        for (int mt = 0; mt < 4; ++mt)
            af[mt] = *(const bf16x8*)&As[(wm + mt * 16 + ln) * 32 + quad * 8];
#pragma unroll
        for (int nt = 0; nt < 4; ++nt)
            bfr[nt] = *(const bf16x8*)&Bs[(wn + nt * 16 + ln) * 32 + quad * 8];
        __builtin_amdgcn_s_setprio(1);
#pragma unroll
        for (int mt = 0; mt < 4; ++mt)
#pragma unroll
            for (int nt = 0; nt < 4; ++nt)
                acc[mt][nt] = MFMA_BF16(af[mt], bfr[nt], acc[mt][nt]);
        __builtin_amdgcn_s_setprio(0);
    }

    if (z == 2) {
        // V epilogue: store transposed per head -> Vt_g[((b*16+h)*64+e)*SEQ + s]
#pragma unroll
        for (int nt = 0; nt < 4; ++nt) {
            const int col = n0 + wn + nt * 16 + ln;       // d
            const int h2 = col >> 6, e = col & 63;
            const float bv = (float)bi[col];
#pragma unroll
            for (int mt = 0; mt < 4; ++mt) {
                const int row = m0 + wm + mt * 16 + quad * 4;
                const int bb = row >> 11, s = row & 2047;
                bf16x4 o = {(bf16)(acc[mt][nt][0] + bv), (bf16)(acc[mt][nt][1] + bv),
                            (bf16)(acc[mt][nt][2] + bv), (bf16)(acc[mt][nt][3] + bv)};
                *(bf16x4*)&Vtg[((size_t)((bb * 16 + h2) * 64 + e)) * SEQ + s] = o;
            }
        }
    } else {
        bf16* C = (z == 0) ? C0 : C1;
#pragma unroll
        for (int nt = 0; nt < 4; ++nt) {
            const int col = n0 + wn + nt * 16 + ln;
            const float bv = (float)bi[col];
#pragma unroll
            for (int mt = 0; mt < 4; ++mt)
#pragma unroll
                for (int r = 0; r < 4; ++r) {
                    const int row = m0 + wm + mt * 16 + quad * 4 + r;
                    C[(size_t)row * DIM + col] = (bf16)(acc[mt][nt][r] + bv);
                }
        }
    }
}

// ---------------------------------------------------------------------------
// Output GEMM (R7 structure) + XCD swizzle: 64x128 tile, 512 blocks = 2/CU.
// ---------------------------------------------------------------------------
__global__ __launch_bounds__(256, 4) void gemm_out_kernel(
    const bf16* __restrict__ A, const bf16* __restrict__ W,
    const bf16* __restrict__ bi, void* __restrict__ C,
    const int* __restrict__ flags)
{
    __shared__ bf16 As[64 * 32];
    __shared__ bf16 Bs[128 * 32];

    const int t = threadIdx.x;
    const bool of32 = flags[0] != 0;

    const int fid = blockIdx.y * gridDim.x + blockIdx.x;   // 0..511
    const int swz = (fid & 7) * 64 + (fid >> 3);           // XCD-contiguous
    const int n0 = (swz & 7) * 128;
    const int m0 = (swz >> 3) * 64;
    const int w    = t >> 6;
    const int lane = t & 63;
    const int ln   = t & 15;
    const int quad = (t >> 4) & 3;
    const int wm   = (w & 1) * 32;
    const int wn   = (w >> 1) * 64;

    const int arow = w * 16 + (lane >> 2);
    const int wrow = w * 32 + (lane >> 2);
    const int scol = (lane & 3) * 8;
    const bf16* gA = A + (size_t)(m0 + arow) * DIM + scol;
    const bf16* gW = W + (size_t)(n0 + wrow) * DIM + scol;
    bf16* lA = &As[(w * 16) * 32];
    bf16* lW = &Bs[(w * 32) * 32];

    f32x4 acc[2][4];
#pragma unroll
    for (int i = 0; i < 2; ++i)
#pragma unroll
        for (int j = 0; j < 4; ++j) acc[i][j] = (f32x4){0.f, 0.f, 0.f, 0.f};

    for (int k0 = 0; k0 < DIM; k0 += 32) {
        __syncthreads();
        glds16(gA + k0,            lA);
        glds16(gW + k0,            lW);
        glds16(gW + 16 * DIM + k0, lW + 16 * 32);
        __syncthreads();

        bf16x8 af[2], bfr[4];
#pragma unroll
        for (int mt = 0; mt < 2; ++mt)
            af[mt] = *(const bf16x8*)&As[(wm + mt * 16 + ln) * 32 + quad * 8];
#pragma unroll
        for (int nt = 0; nt < 4; ++nt)
            bfr[nt] = *(const bf16x8*)&Bs[(wn + nt * 16 + ln) * 32 + quad * 8];
        __builtin_amdgcn_s_setprio(1);
#pragma unroll
        for (int mt = 0; mt < 2; ++mt)
#pragma unroll
            for (int nt = 0; nt < 4; ++nt)
                acc[mt][nt] = MFMA_BF16(af[mt], bfr[nt], acc[mt][nt]);
        __builtin_amdgcn_s_setprio(0);
    }

#pragma unroll
    for (int nt = 0; nt < 4; ++nt) {
        const int col = n0 + wn + nt * 16 + ln;
        const float bv = (float)bi[col];
#pragma unroll
        for (int mt = 0; mt < 2; ++mt)
#pragma unroll
            for (int r = 0; r < 4; ++r) {
                const int row = m0 + wm + mt * 16 + quad * 4 + r;
                if (of32) ((float*)C)[(size_t)row * DIM + col] = acc[mt][nt][r] + bv;
                else      ((bf16*)C)[(size_t)row * DIM + col] = (bf16)(acc[mt][nt][r] + bv);
            }
    }
}

// ---------------------------------------------------------------------------
// Flash attention (R11, measured best 82.4 us): R4's dbuf body + XCD swizzle
// (FETCH 70->12 MB) + setprio + defer-max THR=0. Double-buffered K/V with
// counted vmcnt; P through per-wave swizzled LDS. LDS = 80 KB -> 2 blocks/CU.
// Session note: occupancy/TLP family fully explored (R3-R13) — capacity
// raise, dbuf, chain-shortening, 32x32 shape, and split-K all null or
// regressions; this body is the structural floor for the session.
// ---------------------------------------------------------------------------
__global__ __launch_bounds__(256, 2) void attn_kernel(
    const bf16* __restrict__ Q, const bf16* __restrict__ K,
    const bf16* __restrict__ Vtg, bf16* __restrict__ O)
{
    const int fid = blockIdx.y * gridDim.x + blockIdx.x;   // 0..511
    const int swz = (fid & 7) * 64 + (fid >> 3);           // XCD-contiguous
    const int qt = swz & 15;
    const int bh = swz >> 4;
    const int b  = bh >> 4;
    const int h  = bh & 15;

    __shared__ bf16 Ks[2][128 * 64];
    __shared__ bf16 Vt[2][64 * 128];
    __shared__ bf16 Ps[4 * 16 * 128];

    const int t    = threadIdx.x;
    const int w    = t >> 6;
    const int lane = t & 63;
    const int ln   = lane & 15;
    const int quad = lane >> 4;

    const int q0 = qt * 128;

    const float sc = 0.125f * 1.44269504089f;
    bf16x8 qf[2][2];
#pragma unroll
    for (int g = 0; g < 2; ++g) {
        const bf16* qrow = Q + (size_t)(b * SEQ + q0 + w * 32 + g * 16 + ln) * DIM + h * HDIM;
        qf[g][0] = *(const bf16x8*)(qrow + quad * 8);
        qf[g][1] = *(const bf16x8*)(qrow + 32 + quad * 8);
#pragma unroll
        for (int i = 0; i < 8; ++i) {
            qf[g][0][i] = (bf16)((float)qf[g][0][i] * sc);
            qf[g][1][i] = (bf16)((float)qf[g][1][i] * sc);
        }
    }

    f32x4 o_acc[2][4];
#pragma unroll
    for (int g = 0; g < 2; ++g)
#pragma unroll
        for (int c = 0; c < 4; ++c) o_acc[g][c] = (f32x4){0.f, 0.f, 0.f, 0.f};
    float m_s[2] = {-1e30f, -1e30f};
    float l_s[2] = {0.f, 0.f};

    const int kr_off = lane >> 3;
    const int k_lc   = (lane & 7) ^ kr_off;
    const int ve_off = lane >> 4;
    const int v_pc   = lane & 15;
    const size_t vrowbase = (size_t)((b * 16 + h) * 64);

    const int psbase = (w * 16 + ln) * 128;
    const int pmask  = (ln & 15) << 1;

#define STAGE_KV(BUF, KB)                                                     \
    {                                                                         \
        _Pragma("unroll")                                                     \
        for (int i = 0; i < 4; ++i) {                                         \
            const int r = w * 32 + i * 8 + kr_off;                            \
            glds16(K + (size_t)(b * SEQ + (KB) + r) * DIM + h * HDIM + k_lc * 8, \
                   &Ks[BUF][(w * 32 + i * 8) * 64]);                          \
        }                                                                     \
        _Pragma("unroll")                                                     \
        for (int i = 0; i < 4; ++i) {                                         \
            const int e2 = w * 16 + i * 4 + ve_off;                           \
            const int lc = v_pc ^ (i * 4 + ve_off);                           \
            glds16(Vtg + (vrowbase + e2) * SEQ + (KB) + lc * 8,               \
                   &Vt[BUF][(w * 16 + i * 4) * 128]);                         \
        }                                                                     \
    }

    STAGE_KV(0, 0);

    for (int it = 0; it < SEQ / 128; ++it) {
        const int cur = it & 1;
        if (it < SEQ / 128 - 1) {
            STAGE_KV(cur ^ 1, (it + 1) * 128);
            __asm__ volatile("s_waitcnt vmcnt(8)" ::: "memory");
        } else {
            __asm__ volatile("s_waitcnt vmcnt(0)" ::: "memory");
        }
        __builtin_amdgcn_sched_barrier(0);
        __builtin_amdgcn_s_barrier();
        __builtin_amdgcn_sched_barrier(0);

        f32x4 sa0[8], sa1[8];
        __builtin_amdgcn_s_setprio(1);
#pragma unroll
        for (int nt = 0; nt < 8; ++nt) {
            const int rr = (nt * 16 + ln) * 64;
            const bf16x8 kf0 = *(const bf16x8*)&Ks[cur][rr + ((quad ^ (ln & 7)) << 3)];
            const bf16x8 kf1 = *(const bf16x8*)&Ks[cur][rr + (((quad + 4) ^ (ln & 7)) << 3)];
            f32x4 z0 = (f32x4){0.f, 0.f, 0.f, 0.f};
            z0 = MFMA_BF16(kf0, qf[0][0], z0);
            z0 = MFMA_BF16(kf1, qf[0][1], z0);
            sa0[nt] = z0;
            f32x4 z1 = (f32x4){0.f, 0.f, 0.f, 0.f};
            z1 = MFMA_BF16(kf0, qf[1][0], z1);
            z1 = MFMA_BF16(kf1, qf[1][1], z1);
            sa1[nt] = z1;
        }
        __builtin_amdgcn_s_setprio(0);

#pragma unroll
        for (int g = 0; g < 2; ++g) {
            f32x4* sa = g ? sa1 : sa0;
            float m8[8];
#pragma unroll
            for (int nt = 0; nt < 8; ++nt)
                m8[nt] = fmaxf(fmaxf(sa[nt][0], sa[nt][1]), fmaxf(sa[nt][2], sa[nt][3]));
            float mx = fmaxf(fmaxf(fmaxf(m8[0], m8[1]), fmaxf(m8[2], m8[3])),
                             fmaxf(fmaxf(m8[4], m8[5]), fmaxf(m8[6], m8[7])));
            mx = fmaxf(mx, __shfl_xor(mx, 16));
            mx = fmaxf(mx, __shfl_xor(mx, 32));
            if (!__all(mx <= m_s[g])) {
                const float mn = fmaxf(m_s[g], mx);
                const float al = exp2f(m_s[g] - mn);
                m_s[g] = mn;
                l_s[g] *= al;
#pragma unroll
                for (int r = 0; r < 4; ++r) {
                    const float alr = __shfl(al, quad * 4 + r);
#pragma unroll
                    for (int c = 0; c < 4; ++c) o_acc[g][c][r] *= alr;
                }
            }
            const float mn = m_s[g];
            float r8[8];
#pragma unroll
            for (int nt = 0; nt < 8; ++nt) {
                float p0 = exp2f(sa[nt][0] - mn);
                float p1 = exp2f(sa[nt][1] - mn);
                float p2 = exp2f(sa[nt][2] - mn);
                float p3 = exp2f(sa[nt][3] - mn);
                sa[nt][0] = p0; sa[nt][1] = p1; sa[nt][2] = p2; sa[nt][3] = p3;
                r8[nt] = (p0 + p1) + (p2 + p3);
            }
            float rs = ((r8[0] + r8[1]) + (r8[2] + r8[3])) +
                       ((r8[4] + r8[5]) + (r8[6] + r8[7]));
            rs += __shfl_xor(rs, 16);
            rs += __shfl_xor(rs, 32);
            l_s[g] += rs;
        }

#pragma unroll
        for (int nt = 0; nt < 8; ++nt) {
            bf16x4 pk = {(bf16)sa0[nt][0], (bf16)sa0[nt][1],
                         (bf16)sa0[nt][2], (bf16)sa0[nt][3]};
            *(bf16x4*)&Ps[psbase + (((nt * 4 + quad) ^ pmask) << 2)] = pk;
        }
        __asm__ volatile("s_waitcnt lgkmcnt(0)" ::: "memory");
        bf16x8 pf0[4];
#pragma unroll
        for (int kc = 0; kc < 4; ++kc)
            pf0[kc] = *(const bf16x8*)&Ps[psbase + (((kc * 8 + quad * 2) ^ pmask) << 2)];
        __asm__ volatile("s_waitcnt lgkmcnt(0)" ::: "memory");
#pragma unroll
        for (int nt = 0; nt < 8; ++nt) {
            bf16x4 pk = {(bf16)sa1[nt][0], (bf16)sa1[nt][1],
                         (bf16)sa1[nt][2], (bf16)sa1[nt][3]};
            *(bf16x4*)&Ps[psbase + (((nt * 4 + quad) ^ pmask) << 2)] = pk;
        }
        bf16x8 vf[4][4];
#pragma unroll
        for (int kc = 0; kc < 4; ++kc)
#pragma unroll
            for (int c = 0; c < 4; ++c) {
                const int e = c * 16 + ln;
                const int pc = (kc * 4 + quad) ^ ln;
                vf[kc][c] = *(const bf16x8*)&Vt[cur][e * 128 + pc * 8];
            }
        __asm__ volatile("s_waitcnt lgkmcnt(0)" ::: "memory");

        __builtin_amdgcn_s_setprio(1);
#pragma unroll
        for (int kc = 0; kc < 4; ++kc)
#pragma unroll
            for (int c = 0; c < 4; ++c)
                o_acc[0][c] = MFMA_BF16(pf0[kc], vf[kc][c], o_acc[0][c]);
        __builtin_amdgcn_s_setprio(0);
        bf16x8 pf1[4];
#pragma unroll
        for (int kc = 0; kc < 4; ++kc)
            pf1[kc] = *(const bf16x8*)&Ps[psbase + (((kc * 8 + quad * 2) ^ pmask) << 2)];
        __asm__ volatile("s_waitcnt lgkmcnt(0)" ::: "memory");
        __builtin_amdgcn_s_setprio(1);
#pragma unroll
        for (int kc = 0; kc < 4; ++kc)
#pragma unroll
            for (int c = 0; c < 4; ++c)
                o_acc[1][c] = MFMA_BF16(pf1[kc], vf[kc][c], o_acc[1][c]);
        __builtin_amdgcn_s_setprio(0);

        __builtin_amdgcn_sched_barrier(0);
        __builtin_amdgcn_s_barrier();
    }
#undef STAGE_KV

#pragma unroll
    for (int g = 0; g < 2; ++g) {
        const float linv = 1.0f / l_s[g];
#pragma unroll
        for (int r = 0; r < 4; ++r) {
            const float lr = __shfl(linv, quad * 4 + r);
            const size_t rowoff =
                (size_t)(b * SEQ + q0 + w * 32 + g * 16 + quad * 4 + r) * DIM + h * HDIM;
#pragma unroll
            for (int c = 0; c < 4; ++c)
                O[rowoff + c * 16 + ln] = (bf16)(o_acc[g][c][r] * lr);
        }
    }
}

extern "C" void kernel_launch(void* const* d_in, const int* in_sizes, int n_in,
                              void* d_out, int out_size, void* d_ws, size_t ws_size,
                              hipStream_t stream) {
    // ws layout (bf16 elems): Qb,Kb,Vtg (4.19M each), qc,kc,vc (4.19M each;
    // qc is re-used as Ob after gemm_qkv has consumed it), Wq..Wo (1.05M
    // each), biases (1K each), flags. Total ~59 MB.
    const size_t NM = (size_t)MROWS * DIM;     // 4194304
    const size_t NW = (size_t)DIM * DIM;       // 1048576
    bf16* Qb  = (bf16*)d_ws;
    bf16* Kb  = Qb + NM;
    bf16* Vtg = Kb + NM;
    bf16* qc  = Vtg + NM;
    bf16* kc  = qc + NM;
    bf16* vc  = kc + NM;
    bf16* Wqc = vc + NM;
    bf16* Wkc = Wqc + NW;
    bf16* Wvc = Wkc + NW;
    bf16* Woc = Wvc + NW;
    bf16* bqc = Woc + NW;
    bf16* bkc = bqc + 1024;
    bf16* bvc = bkc + 1024;
    bf16* boc = bvc + 1024;
    int*  flags = (int*)(boc + 1024);
    bf16* Ob  = qc;   // alias: qc dead after gemm_qkv, Ob written by attn

    convert_kernel<<<dim3(2052), 256, 0, stream>>>(
        d_in[0], d_in[1], d_in[2],
        d_in[3], d_in[5], d_in[7], d_in[9],
        d_in[4], d_in[6], d_in[8], d_in[10],
        qc, kc, vc, Wqc, Wkc, Wvc, Woc, bqc, bkc, bvc, boc, flags);

    gemm_qkv_kernel<<<dim3(DIM / 128, MROWS / 128, 3), 256, 0, stream>>>(
        qc, Wqc, bqc, Qb,
        kc, Wkc, bkc, Kb,
        vc, Wvc, bvc, Vtg);

    attn_kernel<<<dim3(SEQ / 128, BATCH * 16), 256, 0, stream>>>(Qb, Kb, Vtg, Ob);

    gemm_out_kernel<<<dim3(DIM / 128, MROWS / 64), 256, 0, stream>>>(
        Ob, Woc, boc, d_out, flags);
}